// Round 8
// baseline (1909.067 us; speedup 1.0000x reference)
//
#include <hip/hip_runtime.h>
#include <math.h>

#define Bsz 512
#define Fsz 64
#define Hsz 256
#define TSTEPS 128
#define G3 768

#define BG 16            // batch groups (32 rows each)
#define NBLK 128         // 16 bg x 8 col-blocks (32 cols each)
#define NTHR 256         // 4 waves: wv = nt*2 + m ; wave owns (m-half, 16-col slice), FULL K
#define SMEM_BYTES (144*1024)

typedef float f32x4 __attribute__((ext_vector_type(4)));
typedef short s16x8 __attribute__((ext_vector_type(8)));
typedef unsigned int  u32x4 __attribute__((ext_vector_type(4)));

#define MF(a,b,c) __builtin_amdgcn_mfma_f32_16x16x32_bf16(a,b,c,0,0,0)

static __device__ __forceinline__ unsigned short bf16_rne(float f){
    union { float f; unsigned u; } v; v.f = f;
    return (unsigned short)((v.u + 0x7FFFu + ((v.u >> 16) & 1u)) >> 16);
}
static __device__ __forceinline__ float bf16_to_f(unsigned short h){
    union { unsigned u; float f; } v; v.u = ((unsigned)h) << 16; return v.f;
}
static __device__ __forceinline__ void split8(const float* p, s16x8& hi, s16x8& lo){
    #pragma unroll
    for (int t = 0; t < 8; ++t){
        float f = p[t];
        unsigned short h = bf16_rne(f);
        hi[t] = (short)h;
        lo[t] = (short)bf16_rne(f - bf16_to_f(h));
    }
}
// fast transcendentals (verified R4: absmax unchanged)
static __device__ __forceinline__ float sigmoidf_(float v){
    return __builtin_amdgcn_rcpf(1.0f + __builtin_amdgcn_exp2f(-1.44269504f*v));
}
static __device__ __forceinline__ float tanhf_(float v){
    return 1.0f - 2.0f*__builtin_amdgcn_rcpf(1.0f + __builtin_amdgcn_exp2f(2.88539008f*v));
}

// ---- MALL-coherent (cache-bypass) ops ----
__device__ __forceinline__ u32x4 load_sys_b128u(const unsigned* p){
    u32x4 r;
    asm volatile("global_load_dwordx4 %0, %1, off sc0 sc1" : "=v"(r) : "v"(p) : "memory");
    return r;
}
__device__ __forceinline__ void store_sys_b32u(unsigned* p, unsigned v){
    asm volatile("global_store_dword %0, %1, off sc0 sc1" :: "v"(p), "v"(v) : "memory");
}
__device__ __forceinline__ int load_sys_i32(const int* p){
    int r;
    asm volatile("global_load_dword %0, %1, off sc0 sc1\n\ts_waitcnt vmcnt(0)"
                 : "=v"(r) : "v"(p) : "memory");
    return r;
}
__device__ __forceinline__ void waitcnt0(){ asm volatile("s_waitcnt vmcnt(0)" ::: "memory"); }
__device__ __forceinline__ void regbar(u32x4& v){ asm volatile("" : "+v"(v)); }

static __device__ __forceinline__ void unpack8(const u32x4 a, const u32x4 b, s16x8& hi, s16x8& lo){
    #pragma unroll
    for (int e = 0; e < 4; ++e){
        hi[e]   = (short)(a[e] >> 16);  lo[e]   = (short)(a[e] & 0xFFFFu);
        hi[4+e] = (short)(b[e] >> 16);  lo[4+e] = (short)(b[e] & 0xFFFFu);
    }
}

// ---------------- setup: M = dec_Wih@reg_W, cfold = dec_Wih@reg_b + dec_bih,
// ---------------- gi0 = x[:,127,:]@dec_Wih.T + dec_bih
extern "C" __global__ void gru_setup(const float* __restrict__ x,
                                     const float* __restrict__ dWih,
                                     const float* __restrict__ dbih,
                                     const float* __restrict__ regW,
                                     const float* __restrict__ regb,
                                     float* __restrict__ Mw,
                                     float* __restrict__ cfold,
                                     float* __restrict__ gi0)
{
    int idx = blockIdx.x*blockDim.x + threadIdx.x;
    if (idx < G3*Hsz) {
        int g = idx >> 8, j = idx & 255;
        float a = 0.f;
        #pragma unroll 8
        for (int f = 0; f < Fsz; ++f) a += dWih[g*Fsz + f]*regW[f*Hsz + j];
        Mw[idx] = a;
    } else if (idx < G3*Hsz + G3) {
        int g = idx - G3*Hsz;
        float a = dbih[g];
        #pragma unroll 8
        for (int f = 0; f < Fsz; ++f) a += dWih[g*Fsz + f]*regb[f];
        cfold[g] = a;
    } else {
        int e = idx - (G3*Hsz + G3);
        if (e < Bsz*G3) {
            int b = e / G3, g = e - b*G3;
            const float* xp = x + (size_t)b*(256*64) + 127*64;
            float a = dbih[g];
            #pragma unroll 8
            for (int f = 0; f < Fsz; ++f) a += xp[f]*dWih[g*Fsz + f];
            gi0[e] = a;
        }
    }
}

// ---------------- persistent GRU: autonomous waves, NO intra-block barriers ----------------
// Wave = (m-half, 16-col slice) with FULL K=256: accumulators complete -> in-register EW.
// Weights: pre-split hi/lo B-fragments in LDS (1KB units, lane-contiguous b128 reads).
// Sync: 2-bit gen tag in each packed h word (tags authoritative, R4 scheme) + per-wave
// flag as miss-gate. Row-groups (bg, m) are fully independent recurrences (16 waves each).
// Ring-2 safety: validating h^g over rows m x ALL 256 cols covers every producer wave of
// the row-group => they finished reading h^{g-1} => its slot is dead before we overwrite.
extern "C" __global__ void __launch_bounds__(NTHR, 1)
gru_persistent(const float* __restrict__ x,
               const float* __restrict__ eWih, const float* __restrict__ eWhh,
               const float* __restrict__ ebih, const float* __restrict__ ebhh,
               const float* __restrict__ dWhh, const float* __restrict__ dbhh,
               const float* __restrict__ Mw,   const float* __restrict__ cfold,
               const float* __restrict__ gi0,  const float* __restrict__ regW,
               const float* __restrict__ regb,
               unsigned* __restrict__ hbuf, unsigned* __restrict__ canary,
               float* __restrict__ out)
{
    extern __shared__ char lds[];
    s16x8* s_aux = (s16x8*)lds;

    const int tid  = threadIdx.x;
    const int wv   = tid >> 6;
    const int lane = tid & 63;
    const int quad = lane >> 4;
    const int lcol = lane & 15;
    const int m    = wv & 1;          // row half
    const int nt   = wv >> 1;         // 16-col slice within block
    const int bg   = blockIdx.x & 15;
    const int hb   = blockIdx.x >> 4; // 0..7 -> cols [hb*32, +32)
    const int c    = hb*32 + nt*16 + lcol;       // this lane's hidden column
    const int m_o  = hb >> 2, nc = hb & 3;       // out-GEMM tile of this block
    const bool outw = (m == m_o) && (nt == 1);   // the wave doing the out-GEMM

    unsigned* myflag = canary + (bg*32 + m*16 + hb*2 + nt);
    const int* fp = (const int*)canary + (bg*32 + m*16 + (lane & 15));

    // ---- encoder B-fragments -> LDS: Whh bases 0..47 ((gate*2+nt)*8+kt), Wih 48..59 ----
    for (int b = wv; b < 60; b += 4){
        const float* src; int u;
        if (b < 48){
            int gate = b >> 4, nt2 = (b >> 3) & 1, kt = b & 7;
            src = eWhh + (size_t)(gate*256 + hb*32 + nt2*16 + lcol)*256 + kt*32 + quad*8;
            u = b;
        } else {
            int b2 = b - 48, gate = b2 >> 2, nt2 = (b2 >> 1) & 1, kx = b2 & 1;
            src = eWih + (size_t)(gate*256 + hb*32 + nt2*16 + lcol)*64 + kx*32 + quad*8;
            u = 48 + b2;
        }
        s16x8 hi, lo; split8(src, hi, lo);
        s_aux[(2*u)*64 + lane] = hi;
        s_aux[(2*u+1)*64 + lane] = lo;
    }
    float bR  = ebih[c]     + ebhh[c];
    float bZ  = ebih[256+c] + ebhh[256+c];
    float bNi = ebih[512+c];
    float bNh = ebhh[512+c];
    float bo  = 0.f;
    float gR[4], gZ[4], gN[4];
    float hold[4] = {0.f, 0.f, 0.f, 0.f};
    __syncthreads();

    for (int g = 0; g <= 2*TSTEPS; ++g){
        const bool enc  = (g < TSTEPS);
        const bool last = (g == 2*TSTEPS);
        const unsigned tag  = (unsigned)((g >> 1) & 3);
        const unsigned otag = (unsigned)(((g+1) >> 1) & 3);
        const unsigned* hin = hbuf + (size_t)(g & 1)*Bsz*Hsz;
        unsigned* hout = hbuf + (size_t)((g+1) & 1)*Bsz*Hsz;

        // ---- transitions (one-time; only places with __syncthreads) ----
        if (g == TSTEPS){
            __syncthreads();
            // decoder bases: gp' 0=R(pure) 1=Z(pure) 2=Wn 3=Mn -> 0..63; regW -> 64..71
            for (int b = wv; b < 72; b += 4){
                const float* src; int u;
                if (b < 64){
                    int gp_ = b >> 4, nt2 = (b >> 3) & 1, kt = b & 7;
                    int col2 = hb*32 + nt2*16 + lcol;
                    size_t ko = (size_t)kt*32 + quad*8;
                    if (gp_ < 2)       src = dWhh + (size_t)(gp_*256 + col2)*256 + ko;
                    else if (gp_ == 2) src = dWhh + (size_t)(512 + col2)*256 + ko;
                    else               src = Mw   + (size_t)(512 + col2)*256 + ko;
                    u = b;
                } else {
                    int kt = b - 64;
                    src = regW + (size_t)(nc*16 + lcol)*256 + kt*32 + quad*8;
                    u = 64 + kt;
                }
                s16x8 hi, lo; split8(src, hi, lo);
                s_aux[(2*u)*64 + lane] = hi;
                s_aux[(2*u+1)*64 + lane] = lo;
            }
            __syncthreads();
            bR  = cfold[c]     + dbhh[c];
            bZ  = cfold[256+c] + dbhh[256+c];
            bNi = cfold[512+c];
            bNh = dbhh[512+c];
            bo  = regb[nc*16 + lcol];
            float dR = dbhh[c], dZ = dbhh[256+c];
            #pragma unroll
            for (int j = 0; j < 4; ++j){
                const float* gp = gi0 + (size_t)(bg*32 + m*16 + quad*4 + j)*G3 + c;
                gR[j] = gp[0] + dR; gZ[j] = gp[256] + dZ; gN[j] = gp[512];
            }
        }
        if (g == TSTEPS + 1){
            __syncthreads();
            for (int b = wv; b < 32; b += 4){   // fold M into R,Z weights
                int gp_ = b >> 4, nt2 = (b >> 3) & 1, kt = b & 7;
                int col2 = hb*32 + nt2*16 + lcol;
                size_t o = (size_t)(gp_*256 + col2)*256 + kt*32 + quad*8;
                float tmp[8];
                #pragma unroll
                for (int t2 = 0; t2 < 8; ++t2) tmp[t2] = dWhh[o+t2] + Mw[o+t2];
                s16x8 hi, lo; split8(tmp, hi, lo);
                s_aux[(2*b)*64 + lane] = hi;
                s_aux[(2*b+1)*64 + lane] = lo;
            }
            __syncthreads();
        }
        if (last && !outw) break;

        // ---- speculative A-fragment loads: full K (16 x dwordx4) ----
        const unsigned* ab = hin + (size_t)(bg*32 + m*16 + lcol)*256 + quad*8;
        u32x4 t[16];
        #pragma unroll
        for (int kt = 0; kt < 8; ++kt){
            t[2*kt]   = load_sys_b128u(ab + kt*32);
            t[2*kt+1] = load_sys_b128u(ab + kt*32 + 4);
        }
        // enc x loads (normal cached), overlap with the MALL RT
        f32x4 xa0, xa1, xb0, xb1;
        if (enc){
            const float* xp = x + (size_t)(bg*32 + m*16 + lcol)*(256*64) + (size_t)g*64 + quad*8;
            xa0 = *(const f32x4*)xp;      xa1 = *(const f32x4*)(xp + 4);
            xb0 = *(const f32x4*)(xp+32); xb1 = *(const f32x4*)(xp + 36);
        }

        // ---- tag validation (R4 scheme; flag-gate only on miss) ----
        #define UPD16() { \
            _Pragma("unroll") \
            for (int i2 = 0; i2 < 16; ++i2) \
                if (!((done >> i2) & 1u)){ \
                    unsigned xx = (t[i2][0]^tag)|(t[i2][1]^tag)|(t[i2][2]^tag)|(t[i2][3]^tag); \
                    if ((xx & 3u) == 0u) done |= (1u << i2); } }
        {
            unsigned done = 0;
            waitcnt0();
            #pragma unroll
            for (int i2 = 0; i2 < 16; ++i2) regbar(t[i2]);
            UPD16();
            if (!__all((int)(done == 0xFFFFu))){
                while (1){
                    int v = (int)g;
                    if (lane < 16) v = load_sys_i32(fp);
                    if (__all((int)((lane >= 16) | (v >= (int)g)))) break;
                    __builtin_amdgcn_s_sleep(1);
                }
                while (1){
                    #pragma unroll
                    for (int i2 = 0; i2 < 16; ++i2)
                        if (!((done >> i2) & 1u))
                            t[i2] = load_sys_b128u(ab + (i2 >> 1)*32 + (i2 & 1)*4);
                    waitcnt0();
                    #pragma unroll
                    for (int i2 = 0; i2 < 16; ++i2) regbar(t[i2]);
                    UPD16();
                    if (__all((int)(done == 0xFFFFu))) break;
                    __builtin_amdgcn_s_sleep(1);
                }
            }
        }
        #undef UPD16

        // ---- accumulator init (biases broadcast; g==128 from gi0) ----
        f32x4 aR4, aZ4, aNi4, aNh4, oa;
        aNh4 = (f32x4){bNh, bNh, bNh, bNh};
        oa   = (f32x4){bo, bo, bo, bo};
        if (enc || g > TSTEPS){
            aR4  = (f32x4){bR, bR, bR, bR};
            aZ4  = (f32x4){bZ, bZ, bZ, bZ};
            aNi4 = (f32x4){bNi, bNi, bNi, bNi};
        } else {
            #pragma unroll
            for (int j = 0; j < 4; ++j){ aR4[j] = gR[j]; aZ4[j] = gZ[j]; aNi4[j] = gN[j]; }
        }

        // ---- x-GEMM (enc): K=64, B from LDS ----
        if (enc){
            float xf[8]; s16x8 xh, xl;
            #pragma unroll
            for (int kx = 0; kx < 2; ++kx){
                if (kx == 0){
                    #pragma unroll
                    for (int e = 0; e < 4; ++e){ xf[e] = xa0[e]; xf[4+e] = xa1[e]; }
                } else {
                    #pragma unroll
                    for (int e = 0; e < 4; ++e){ xf[e] = xb0[e]; xf[4+e] = xb1[e]; }
                }
                split8(xf, xh, xl);
                #pragma unroll
                for (int gate = 0; gate < 3; ++gate){
                    int u = 48 + (gate*2 + nt)*2 + kx;
                    s16x8 bh = s_aux[(2*u)*64 + lane];
                    s16x8 bl = s_aux[(2*u+1)*64 + lane];
                    f32x4* A = (gate == 0) ? &aR4 : (gate == 1) ? &aZ4 : &aNi4;
                    *A = MF(xh, bh, *A); *A = MF(xh, bl, *A); *A = MF(xl, bh, *A);
                }
            }
        }

        // ---- h-GEMMs: full K, B streamed from LDS; out-GEMM shares A-frags ----
        #pragma unroll
        for (int kt = 0; kt < 8; ++kt){
            s16x8 ah, al;
            unpack8(t[2*kt], t[2*kt+1], ah, al);
            if (!last){
                #pragma unroll
                for (int gate = 0; gate < 3; ++gate){
                    int u = ((gate*2 + nt)*8 + kt)*2;
                    s16x8 bh = s_aux[u*64 + lane];
                    s16x8 bl = s_aux[(u+1)*64 + lane];
                    f32x4* A = (gate == 0) ? &aR4 : (gate == 1) ? &aZ4 : &aNh4;
                    *A = MF(ah, bh, *A); *A = MF(ah, bl, *A); *A = MF(al, bh, *A);
                }
                if (!enc && g > TSTEPS){   // Ni += M_n @ h
                    int u = ((3*2 + nt)*8 + kt)*2;
                    s16x8 bh = s_aux[u*64 + lane];
                    s16x8 bl = s_aux[(u+1)*64 + lane];
                    aNi4 = MF(ah, bh, aNi4); aNi4 = MF(ah, bl, aNi4); aNi4 = MF(al, bh, aNi4);
                }
            }
            if (outw && g > TSTEPS){       // out tile (full K on this wave)
                int u = (64 + kt)*2;
                s16x8 bh = s_aux[u*64 + lane];
                s16x8 bl = s_aux[(u+1)*64 + lane];
                oa = MF(ah, bh, oa); oa = MF(ah, bl, oa); oa = MF(al, bh, oa);
            }
        }

        // ---- in-register elementwise + tagged h stores + flag (no barrier!) ----
        if (!last){
            #pragma unroll
            for (int j = 0; j < 4; ++j){
                float r = sigmoidf_(aR4[j]);
                float z = sigmoidf_(aZ4[j]);
                float n = tanhf_(aNi4[j] + r*aNh4[j]);
                float hv = (1.0f - z)*n + z*hold[j];
                unsigned short p1 = bf16_rne(hv);
                unsigned short p0 = (unsigned short)((bf16_rne(hv - bf16_to_f(p1)) & 0xFFFCu) | otag);
                store_sys_b32u(hout + (size_t)(bg*32 + m*16 + quad*4 + j)*256 + c,
                               (((unsigned)p1) << 16) | (unsigned)p0);
                hold[j] = bf16_to_f(p1) + bf16_to_f(p0);
            }
            if (lane == 0) store_sys_b32u(myflag, (unsigned)(g + 1));
        }

        // ---- out_{g-129} store ----
        if (outw && g > TSTEPS){
            const int oi = g - TSTEPS - 1;
            #pragma unroll
            for (int j = 0; j < 4; ++j)
                out[(size_t)(bg*32 + m_o*16 + quad*4 + j)*(TSTEPS*Fsz)
                    + (size_t)oi*Fsz + nc*16 + lcol] = oa[j];
        }
    }
}

extern "C" void kernel_launch(void* const* d_in, const int* in_sizes, int n_in,
                              void* d_out, int out_size, void* d_ws, size_t ws_size,
                              hipStream_t stream)
{
    (void)in_sizes; (void)n_in; (void)out_size; (void)ws_size;
    const float* x    = (const float*)d_in[0];
    const float* eWih = (const float*)d_in[1];
    const float* eWhh = (const float*)d_in[2];
    const float* ebih = (const float*)d_in[3];
    const float* ebhh = (const float*)d_in[4];
    const float* dWih = (const float*)d_in[5];
    const float* dWhh = (const float*)d_in[6];
    const float* dbih = (const float*)d_in[7];
    const float* dbhh = (const float*)d_in[8];
    const float* regW = (const float*)d_in[9];
    const float* regb = (const float*)d_in[10];
    float* out = (float*)d_out;

    unsigned* hbuf = (unsigned*)d_ws;                    // 2 slots of 512x256 packed bf16-pairs
    float* Mw    = (float*)d_ws + 2*Bsz*Hsz;             // 768*256
    float* gi0   = Mw + G3*Hsz;                          // 512*768
    float* cfold = gi0 + (size_t)Bsz*G3;                 // 768 (+pad)
    unsigned* canary = (unsigned*)(cfold + 1024);        // 16 bg x 32 wave-flags

    // slot0 = h^0 = 0 (tag 0 == tag(gen0)); slot1 = 0x03 bytes (tag 3 != tag(gen1)=0)
    hipMemsetAsync(hbuf, 0, (size_t)Bsz*Hsz*sizeof(unsigned), stream);
    hipMemsetAsync(hbuf + (size_t)Bsz*Hsz, 3, (size_t)Bsz*Hsz*sizeof(unsigned), stream);
    hipMemsetAsync(canary, 0, (size_t)BG*32*sizeof(unsigned), stream);

    hipLaunchKernelGGL(gru_setup, dim3(2307), dim3(256), 0, stream,
                       x, dWih, dbih, regW, regb, Mw, cfold, gi0);

    hipFuncSetAttribute((const void*)gru_persistent,
                        hipFuncAttributeMaxDynamicSharedMemorySize, SMEM_BYTES);

    void* args[] = { (void*)&x, (void*)&eWih, (void*)&eWhh, (void*)&ebih, (void*)&ebhh,
                     (void*)&dWhh, (void*)&dbhh, (void*)&Mw, (void*)&cfold, (void*)&gi0,
                     (void*)&regW, (void*)&regb, (void*)&hbuf, (void*)&canary, (void*)&out };
    hipError_t rc = hipLaunchCooperativeKernel((const void*)gru_persistent,
                                               dim3(NBLK), dim3(NTHR), args,
                                               SMEM_BYTES, stream);
    if (rc != hipSuccess) {
        hipLaunchKernelGGL(gru_persistent, dim3(NBLK), dim3(NTHR), SMEM_BYTES, stream,
                           x, eWih, eWhh, ebih, ebhh, dWhh, dbhh, Mw, cfold, gi0,
                           regW, regb, hbuf, canary, out);
    }
}